// Round 9
// baseline (100.292 us; speedup 1.0000x reference)
//
#include <hip/hip_runtime.h>
#include <hip/hip_bf16.h>

#define NATOMS 2048
#define K 48
#define NR 5
#define NM 12
#define ND 17
#define HID 64

#define PI_F 3.14159265358979f
#define CUT 3.0f
#define RMIN_F 3.5f
#define AFC (-6.28318530717959f)   /* pi/(CUT-RMIN) = pi/(-0.5) */
#define POC (PI_F / CUT)           /* pi/3 */
#define SQ 0.816496580927726f      /* sqrt(2/3) */
#define CMC (-0.132231404958678f)  /* -16/121 */
/* exp2-folded constants (x * log2(e)) */
#define N4L (-5.77078016355585f)   /* -4 * log2e */
#define E1L (2.09846551402031f)    /* (16/11) * log2e */
#define TL2 (2.88539008177793f)    /* 2 * log2e */

// Packed bf16 weight layouts (built once per launch by k_prep).
__device__ unsigned short g_w1t[64 * 32];  // [n=h][k=j]  (k>=17 zero)
__device__ unsigned short g_w2t[64 * 64];  // [n=h2][k=h1]
__device__ unsigned short g_w2r[64 * 64];  // [n=h1][k=h2]
__device__ unsigned short g_w1r[32 * 64];  // [n=j][k=h]  (n>=17 zero)

using frag_ab = __attribute__((ext_vector_type(8))) short;
using frag_cd = __attribute__((ext_vector_type(4))) float;
using f2 = __attribute__((ext_vector_type(2))) float;
using f4 = __attribute__((ext_vector_type(4))) float;

__device__ __forceinline__ float fast_tanh(float x) {
    const float t = __builtin_amdgcn_exp2f(TL2 * x);
    return 1.0f - 2.0f * __builtin_amdgcn_rcpf(t + 1.0f);
}

__device__ __forceinline__ unsigned short f2bs(float x) {
    __hip_bfloat16 b = __float2bfloat16(x);
    return __builtin_bit_cast(unsigned short, b);
}

__device__ __forceinline__ float bs2f(unsigned short u) {
    return __builtin_bit_cast(float, ((unsigned)u) << 16);
}

// DPP cross-lane add. 0xB1/0x4E = quad_perm xor1/xor2 (butterfly, all lanes
// get the sum). 0x110|s = row_shr s (16-lane sum lands in lane 15).
template <int CTRL>
__device__ __forceinline__ float dpp_add(float x) {
    const int y = __builtin_amdgcn_update_dpp(
        0, __builtin_bit_cast(int, x), CTRL, 0xF, 0xF, true);
    return x + __builtin_bit_cast(float, y);
}

// ---------------- Kernel 0: pack weights into MFMA-ready bf16 layouts -----
__global__ __launch_bounds__(256) void k_prep(const float* __restrict__ W1,
                                              const float* __restrict__ W2) {
    const int i = blockIdx.x * 256 + threadIdx.x;  // grid covers 12288
    if (i < 2048) {                                   // W1T[n][k]
        const int n = i >> 5, k = i & 31;
        g_w1t[i] = (k < ND) ? f2bs(W1[k * HID + n]) : (unsigned short)0;
    } else if (i < 2048 + 4096) {                     // W2T[n][k]
        const int j = i - 2048, n = j >> 6, k = j & 63;
        g_w2t[j] = f2bs(W2[k * HID + n]);
    } else if (i < 2048 + 8192) {                     // W2R[n][k]
        const int j = i - (2048 + 4096);
        g_w2r[j] = f2bs(W2[j]);
    } else if (i < 2048 + 8192 + 2048) {              // W1R[n][k]
        const int j = i - (2048 + 8192), n = j >> 6;
        g_w1r[j] = (n < ND) ? f2bs(W1[j]) : (unsigned short)0;
    }
}

// ---------------- Fused kernel: 1 atom / 3 waves / ONE barrier ------------
// Wave w owns rows 16w..16w+15. X is a single reused transpose buffer:
// desc -> h1 -> gz2 -> gz1 (each stage reads its A-frags then overwrites;
// write values are data-dependent on the reads + per-wave DS in-order =>
// race-free; cross-wave: strict row ownership). Geometry (su/sfk/sfc) is
// computed redundantly by every wave (identical values, benign) so no
// barrier is needed before the MLP. The single __syncthreads sits between
// bwd2 (all sgd rows written) and pass B (reads all rows' gm).
// LDS 11,904 B -> 8 blocks/CU resident -> 24 waves/CU (6/SIMD).
//  X   @0     (6912): [48][72] bf16
//  SGD @6912  (3840): [48][20] f32: 0-4 radial, 5 eij, 8..19 gm (C_m-scaled)
//  SU  @10752 (768): [4k+{x,y,z,d}]
//  SFC @11520 (192), SFK @11712 (192)
#define XS       72
#define X_OFF    0
#define SGD_OFF  6912
#define SU_OFF   10752
#define SFC_OFF  11520
#define SFK_OFF  11712
#define SM_BYTES 11904

__global__ __launch_bounds__(192, 6) void k_fused(const float* __restrict__ rij,
                                                  const float* __restrict__ b1,
                                                  const float* __restrict__ b2,
                                                  const float* __restrict__ W3,
                                                  const float* __restrict__ b3,
                                                  float* __restrict__ out) {
    __shared__ __align__(16) char smem[SM_BYTES];
    short* X   = (short*)(smem + X_OFF);    // [row*72+col] bf16
    float* sgd = (float*)(smem + SGD_OFF);  // [row*20+col]
    float* su  = (float*)(smem + SU_OFF);
    float* sfc = (float*)(smem + SFC_OFF);
    float* sfk = (float*)(smem + SFK_OFF);

    const int t = threadIdx.x;
    const int w = t >> 6, lane = t & 63, quad = lane >> 4, lm = lane & 15;
    const int row0 = 16 * w;
    const int base3 = blockIdx.x * (K * 3);

    float b1v[4], b2v[4], w3v[4];
#pragma unroll
    for (int nt = 0; nt < 4; nt++) {
        b1v[nt] = b1[nt * 16 + lm];
        b2v[nt] = b2[nt * 16 + lm];
        w3v[nt] = W3[nt * 16 + lm];
    }
    const float b3v = b3[0];

    // ---- ph0: geometry (duplicated per wave); own rows: rbf + K-pad ----
    if (lane < K) {
        const float x = rij[base3 + 3 * lane];
        const float y = rij[base3 + 3 * lane + 1];
        const float z = rij[base3 + 3 * lane + 2];
        float s2 = fmaxf(x * x + y * y + z * z, 1e-24f);
        const float inv = __builtin_amdgcn_rsqf(s2);
        const float d = s2 * inv;
        *(f4*)&su[4 * lane] = (f4){x * inv, y * inv, z * inv, d};
        sfk[lane] = 0.5f + 0.5f * __cosf(POC * d);
        const float fc = (d > RMIN_F) ? (0.5f + 0.5f * __cosf(AFC * (d - RMIN_F))) : 1.0f;
        sfc[lane] = fc;
        if ((lane >> 4) == w) {             // own-tile row: rbf + pad
            float s1, c1;
            __sincosf(POC * d, &s1, &c1);
            const float sc = SQ * fc * inv;
            float sn = s1, cn = c1;
#pragma unroll 1
            for (int n = 0; n < NR; n++) {
                X[lane * XS + n] = (short)f2bs(sc * sn);
                const float snx = sn * c1 + cn * s1;
                cn = cn * c1 - sn * s1;
                sn = snx;
            }
#pragma unroll 1
            for (int c = ND; c < 32; c++) X[lane * XS + c] = 0;  // K-pad
        }
    }

    // ---- ph1: own-tile 3-body descriptors (lane = 4*r16 + ch) ----
    const int r16 = lane >> 2, ch = lane & 3;
    const int kk = row0 + r16;              // owned pair index (used again later)
    const f4 ukk = *(const f4*)&su[4 * kk];
    {
        f2 partv[6];
#pragma unroll
        for (int i = 0; i < 6; i++) partv[i] = (f2){0.0f, 0.0f};
#pragma unroll 1
        for (int li = 0; li < 12; li++) {
            const int l = ch * 12 + li;
            const f4 ul = *(const f4*)&su[4 * l];
            float c = ukk.x * ul.x + ukk.y * ul.y + ukk.z * ul.z;
            if (kk == l) c = 0.0f;
            const float cp1 = c + 1.0f;
            const float e0 = __builtin_amdgcn_exp2f(N4L * cp1 * cp1) * sfk[l];
            const float e1 = __builtin_amdgcn_exp2f(E1L * cp1);
            const float e2s = e1 * e1;
            const f2 e2v = {e2s, e2s};
            f2 tm = {e0, e0 * e1};
            partv[0] += tm;
#pragma unroll
            for (int i = 1; i < 6; i++) { tm *= e2v; partv[i] += tm; }
        }
#pragma unroll
        for (int i = 0; i < 6; i++) {
            partv[i].x = dpp_add<0x4E>(dpp_add<0xB1>(partv[i].x));
            partv[i].y = dpp_add<0x4E>(dpp_add<0xB1>(partv[i].y));
        }
        if (ch == 0) {
#pragma unroll
            for (int i = 0; i < 6; i++) {
                const int m0 = 2 * i, m1 = 2 * i + 1;
                X[kk * XS + NR + m0] = (short)f2bs(partv[i].x * __expf(CMC * (float)(m0 * m0)));
                X[kk * XS + NR + m1] = (short)f2bs(partv[i].y * __expf(CMC * (float)(m1 * m1)));
            }
        }
    }

    // ---- fwd1: h1 = tanh(desc @ W1 + b1); t1 in registers; h1 -> X ----
    float t1v[4][4];
    {
        const frag_ab a = *(const frag_ab*)&X[(row0 + lm) * XS + quad * 8];
#pragma unroll
        for (int nt = 0; nt < 4; nt++) {
            const frag_ab bfr = *(const frag_ab*)&g_w1t[(nt * 16 + lm) * 32 + quad * 8];
            frag_cd acc = {b1v[nt], b1v[nt], b1v[nt], b1v[nt]};
            acc = __builtin_amdgcn_mfma_f32_16x16x32_bf16(a, bfr, acc, 0, 0, 0);
#pragma unroll
            for (int r = 0; r < 4; r++) {
                const float tv = fast_tanh(acc[r]);
                t1v[nt][r] = tv;
                X[(row0 + quad * 4 + r) * XS + nt * 16 + lm] = (short)f2bs(tv);
            }
        }
    }

    // ---- fwd2: t2 = tanh(h1@W2+b2); eij row-sums -> sgd[..5]; gz2 -> X ----
    {
        const frag_ab a0 = *(const frag_ab*)&X[(row0 + lm) * XS + quad * 8];
        const frag_ab a1 = *(const frag_ab*)&X[(row0 + lm) * XS + 32 + quad * 8];
        const f4 fcv = *(const f4*)&sfc[row0 + quad * 4];
        float ep[4] = {0.0f, 0.0f, 0.0f, 0.0f};
#pragma unroll
        for (int nt = 0; nt < 4; nt++) {
            const frag_ab b0 = *(const frag_ab*)&g_w2t[(nt * 16 + lm) * 64 + quad * 8];
            const frag_ab b1f = *(const frag_ab*)&g_w2t[(nt * 16 + lm) * 64 + 32 + quad * 8];
            frag_cd acc = {b2v[nt], b2v[nt], b2v[nt], b2v[nt]};
            acc = __builtin_amdgcn_mfma_f32_16x16x32_bf16(a0, b0, acc, 0, 0, 0);
            acc = __builtin_amdgcn_mfma_f32_16x16x32_bf16(a1, b1f, acc, 0, 0, 0);
#pragma unroll
            for (int r = 0; r < 4; r++) {
                const float tv = fast_tanh(acc[r]);
                ep[r] = fmaf(tv, w3v[nt], ep[r]);
                X[(row0 + quad * 4 + r) * XS + nt * 16 + lm] =
                    (short)f2bs(fcv[r] * w3v[nt] * (1.0f - tv * tv));
            }
        }
#pragma unroll
        for (int r = 0; r < 4; r++)
            ep[r] = dpp_add<0x118>(dpp_add<0x114>(dpp_add<0x112>(dpp_add<0x111>(ep[r]))));
        if (lm == 15) {
#pragma unroll
            for (int r = 0; r < 4; r++)
                sgd[(row0 + quad * 4 + r) * 20 + 5] = ep[r] + b3v;
        }
    }

    // ---- bwd1: gz1 = (gz2 @ W2^T)*(1-t1^2) -> X ----
    {
        const frag_ab a0 = *(const frag_ab*)&X[(row0 + lm) * XS + quad * 8];
        const frag_ab a1 = *(const frag_ab*)&X[(row0 + lm) * XS + 32 + quad * 8];
#pragma unroll
        for (int nt = 0; nt < 4; nt++) {
            const frag_ab b0 = *(const frag_ab*)&g_w2r[(nt * 16 + lm) * 64 + quad * 8];
            const frag_ab b1f = *(const frag_ab*)&g_w2r[(nt * 16 + lm) * 64 + 32 + quad * 8];
            frag_cd acc = {0.0f, 0.0f, 0.0f, 0.0f};
            acc = __builtin_amdgcn_mfma_f32_16x16x32_bf16(a0, b0, acc, 0, 0, 0);
            acc = __builtin_amdgcn_mfma_f32_16x16x32_bf16(a1, b1f, acc, 0, 0, 0);
#pragma unroll
            for (int r = 0; r < 4; r++) {
                const float g = acc[r] * (1.0f - t1v[nt][r] * t1v[nt][r]);
                X[(row0 + quad * 4 + r) * XS + nt * 16 + lm] = (short)f2bs(g);
            }
        }
    }

    // ---- bwd2: gdesc = gz1 @ W1^T -> sgd (radial cols 0-4; gm cols 8-19,
    //      C_m pre-scaled) ----
    {
        const frag_ab a0 = *(const frag_ab*)&X[(row0 + lm) * XS + quad * 8];
        const frag_ab a1 = *(const frag_ab*)&X[(row0 + lm) * XS + 32 + quad * 8];
        {   // nt=0: n = lm (0..15)
            const frag_ab b0 = *(const frag_ab*)&g_w1r[lm * 64 + quad * 8];
            const frag_ab b1f = *(const frag_ab*)&g_w1r[lm * 64 + 32 + quad * 8];
            frag_cd acc = {0.0f, 0.0f, 0.0f, 0.0f};
            acc = __builtin_amdgcn_mfma_f32_16x16x32_bf16(a0, b0, acc, 0, 0, 0);
            acc = __builtin_amdgcn_mfma_f32_16x16x32_bf16(a1, b1f, acc, 0, 0, 0);
            const int col = (lm < NR) ? lm : lm + 3;        // radial | gm slot
            const int mm = lm - NR;
            const float cm = (lm >= NR) ? __expf(CMC * (float)(mm * mm)) : 1.0f;
#pragma unroll
            for (int r = 0; r < 4; r++)
                sgd[(row0 + quad * 4 + r) * 20 + col] = acc[r] * cm;
        }
        {   // nt=1: only n=16 (m=11) is live
            const frag_ab b0 = *(const frag_ab*)&g_w1r[(16 + lm) * 64 + quad * 8];
            const frag_ab b1f = *(const frag_ab*)&g_w1r[(16 + lm) * 64 + 32 + quad * 8];
            frag_cd acc = {0.0f, 0.0f, 0.0f, 0.0f};
            acc = __builtin_amdgcn_mfma_f32_16x16x32_bf16(a0, b0, acc, 0, 0, 0);
            acc = __builtin_amdgcn_mfma_f32_16x16x32_bf16(a1, b1f, acc, 0, 0, 0);
            if (lm == 0) {
                const float cm = __expf(-16.0f);             // CMC*121
#pragma unroll
                for (int r = 0; r < 4; r++)
                    sgd[(row0 + quad * 4 + r) * 20 + 19] = acc[r] * cm;
            }
        }
    }

    // ---- pass A: term1 = sum_l S[k][l]*fk[l]*u[l]  (own-row gm, no bar) ----
    float gx1 = 0.0f, gy1 = 0.0f, gz1 = 0.0f;
    {
        const f4 gA = *(const f4*)&sgd[kk * 20 + 8];
        const f4 gB = *(const f4*)&sgd[kk * 20 + 12];
        const f4 gC = *(const f4*)&sgd[kk * 20 + 16];
#pragma unroll 1
        for (int li = 0; li < 12; li++) {
            const int l = ch * 12 + li;
            const f4 ul = *(const f4*)&su[4 * l];
            float c = ukk.x * ul.x + ukk.y * ul.y + ukk.z * ul.z;
            if (kk == l) c = 0.0f;
            const float cp1 = c + 1.0f;
            const float e0 = __builtin_amdgcn_exp2f(N4L * cp1 * cp1);
            const float x = __builtin_amdgcn_exp2f(E1L * cp1);
            float P = gC[3], Dd = 11.0f * gC[3];
            P = fmaf(P, x, gC[2]); Dd = fmaf(Dd, x, 10.0f * gC[2]);
            P = fmaf(P, x, gC[1]); Dd = fmaf(Dd, x, 9.0f * gC[1]);
            P = fmaf(P, x, gC[0]); Dd = fmaf(Dd, x, 8.0f * gC[0]);
            P = fmaf(P, x, gB[3]); Dd = fmaf(Dd, x, 7.0f * gB[3]);
            P = fmaf(P, x, gB[2]); Dd = fmaf(Dd, x, 6.0f * gB[2]);
            P = fmaf(P, x, gB[1]); Dd = fmaf(Dd, x, 5.0f * gB[1]);
            P = fmaf(P, x, gB[0]); Dd = fmaf(Dd, x, 4.0f * gB[0]);
            P = fmaf(P, x, gA[3]); Dd = fmaf(Dd, x, 3.0f * gA[3]);
            P = fmaf(P, x, gA[2]); Dd = fmaf(Dd, x, 2.0f * gA[2]);
            P = fmaf(P, x, gA[1]); Dd = fmaf(Dd, x, gA[1]);
            P = fmaf(P, x, gA[0]);
            const float T = e0 * P;
            const float U = e0 * x * Dd;
            const float Sp = fmaf(cp1, T, -(2.0f / 11.0f) * U);
            const float Sv = (kk == l) ? 0.0f : (-8.0f) * Sp;
            const float A = Sv * sfk[l];
            gx1 = fmaf(A, ul.x, gx1);
            gy1 = fmaf(A, ul.y, gy1);
            gz1 = fmaf(A, ul.z, gz1);
        }
    }

    __syncthreads();   // THE barrier: all sgd rows visible

    // ---- pass B: transposed sums (gm of row l); combine; write out ----
    {
        float sgfp = 0.0f, gx2 = 0.0f, gy2 = 0.0f, gz2p = 0.0f;
#pragma unroll 1
        for (int li = 0; li < 12; li++) {
            const int l = ch * 12 + li;
            const f4 gA = *(const f4*)&sgd[l * 20 + 8];
            const f4 gB = *(const f4*)&sgd[l * 20 + 12];
            const f4 gC = *(const f4*)&sgd[l * 20 + 16];
            const f4 ul = *(const f4*)&su[4 * l];
            float c = ukk.x * ul.x + ukk.y * ul.y + ukk.z * ul.z;
            if (kk == l) c = 0.0f;
            const float cp1 = c + 1.0f;
            const float e0 = __builtin_amdgcn_exp2f(N4L * cp1 * cp1);
            const float x = __builtin_amdgcn_exp2f(E1L * cp1);
            float P = gC[3], Dd = 11.0f * gC[3];
            P = fmaf(P, x, gC[2]); Dd = fmaf(Dd, x, 10.0f * gC[2]);
            P = fmaf(P, x, gC[1]); Dd = fmaf(Dd, x, 9.0f * gC[1]);
            P = fmaf(P, x, gC[0]); Dd = fmaf(Dd, x, 8.0f * gC[0]);
            P = fmaf(P, x, gB[3]); Dd = fmaf(Dd, x, 7.0f * gB[3]);
            P = fmaf(P, x, gB[2]); Dd = fmaf(Dd, x, 6.0f * gB[2]);
            P = fmaf(P, x, gB[1]); Dd = fmaf(Dd, x, 5.0f * gB[1]);
            P = fmaf(P, x, gB[0]); Dd = fmaf(Dd, x, 4.0f * gB[0]);
            P = fmaf(P, x, gA[3]); Dd = fmaf(Dd, x, 3.0f * gA[3]);
            P = fmaf(P, x, gA[2]); Dd = fmaf(Dd, x, 2.0f * gA[2]);
            P = fmaf(P, x, gA[1]); Dd = fmaf(Dd, x, gA[1]);
            P = fmaf(P, x, gA[0]);
            const float T = e0 * P;                 // T[l][kk] (diag included)
            const float U = e0 * x * Dd;
            const float Sp = fmaf(cp1, T, -(2.0f / 11.0f) * U);
            const float Sv = (kk == l) ? 0.0f : (-8.0f) * Sp;
            sgfp += T;
            gx2 = fmaf(Sv, ul.x, gx2);
            gy2 = fmaf(Sv, ul.y, gy2);
            gz2p = fmaf(Sv, ul.z, gz2p);
        }
        // quad-butterfly reduce the 7 chunk-partials (all lanes get sums)
        gx1 = dpp_add<0x4E>(dpp_add<0xB1>(gx1));
        gy1 = dpp_add<0x4E>(dpp_add<0xB1>(gy1));
        gz1 = dpp_add<0x4E>(dpp_add<0xB1>(gz1));
        sgfp = dpp_add<0x4E>(dpp_add<0xB1>(sgfp));
        gx2 = dpp_add<0x4E>(dpp_add<0xB1>(gx2));
        gy2 = dpp_add<0x4E>(dpp_add<0xB1>(gy2));
        gz2p = dpp_add<0x4E>(dpp_add<0xB1>(gz2p));

        if (ch == 0) {
            const float fk = sfk[kk];
            const float gux = gx1 + fk * gx2;
            const float guy = gy1 + fk * gy2;
            const float guz = gz1 + fk * gz2p;

            const float d = ukk.w;
            const float ux = ukk.x, uy = ukk.y, uz = ukk.z;
            const float invd = __builtin_amdgcn_rcpf(d);
            float gfc = sgd[kk * 20 + 5];
            float gdR = 0.0f;
            float s1, c1;
            __sincosf(POC * d, &s1, &c1);
            float sn = s1, cn = c1, bn = POC;
#pragma unroll 1
            for (int n = 0; n < NR; n++) {
                const float g = sgd[kk * 20 + n];
                gfc = fmaf(g, SQ * sn * invd, gfc);
                gdR = fmaf(g, SQ * (bn * cn - sn * invd) * invd, gdR);
                const float snx = sn * c1 + cn * s1;
                cn = cn * c1 - sn * s1;
                sn = snx;
                bn += POC;
            }
            const float fc = sfc[kk];
            float dfc = 0.0f;
            if (d > RMIN_F) dfc = -0.5f * AFC * __sinf(AFC * (d - RMIN_F));
            const float dfcrik = -0.5f * POC * __sinf(POC * d);

            const float gd = fc * gdR + gfc * dfc + sgfp * dfcrik;
            const float dot = gux * ux + guy * uy + guz * uz;

            out[base3 + 3 * kk + 0] = fmaf(gd, ux, (gux - dot * ux) * invd);
            out[base3 + 3 * kk + 1] = fmaf(gd, uy, (guy - dot * uy) * invd);
            out[base3 + 3 * kk + 2] = fmaf(gd, uz, (guz - dot * uz) * invd);
        }
    }
}

extern "C" void kernel_launch(void* const* d_in, const int* in_sizes, int n_in,
                              void* d_out, int out_size, void* d_ws, size_t ws_size,
                              hipStream_t stream) {
    (void)in_sizes; (void)n_in; (void)out_size; (void)d_ws; (void)ws_size;
    const float* rij = (const float*)d_in[0];
    // d_in[1] = unique_i (unused: dense K neighbors per atom)
    const float* W1 = (const float*)d_in[2];
    const float* b1 = (const float*)d_in[3];
    const float* W2 = (const float*)d_in[4];
    const float* b2 = (const float*)d_in[5];
    const float* W3 = (const float*)d_in[6];
    const float* b3 = (const float*)d_in[7];
    float* out = (float*)d_out;

    k_prep<<<48, 256, 0, stream>>>(W1, W2);
    k_fused<<<NATOMS, 192, 0, stream>>>(rij, b1, b2, W3, b3, out);
}

// Round 10
// 95.469 us; speedup vs baseline: 1.0505x; 1.0505x over previous
//
#include <hip/hip_runtime.h>
#include <hip/hip_bf16.h>

#define NATOMS 2048
#define K 48
#define NR 5
#define NM 12
#define ND 17
#define HID 64

#define PI_F 3.14159265358979f
#define CUT 3.0f
#define RMIN_F 3.5f
#define AFC (-6.28318530717959f)   /* pi/(CUT-RMIN) = pi/(-0.5) */
#define POC (PI_F / CUT)           /* pi/3 */
#define SQ 0.816496580927726f      /* sqrt(2/3) */
#define CMC (-0.132231404958678f)  /* -16/121 */
/* exp2-folded constants (x * log2(e)) */
#define N4L (-5.77078016355585f)   /* -4 * log2e */
#define E1L (2.09846551402031f)    /* (16/11) * log2e */
#define TL2 (2.88539008177793f)    /* 2 * log2e */

using frag_ab = __attribute__((ext_vector_type(8))) short;
using frag_cd = __attribute__((ext_vector_type(4))) float;
using f2 = __attribute__((ext_vector_type(2))) float;
using f4 = __attribute__((ext_vector_type(4))) float;

__device__ __forceinline__ float fast_tanh(float x) {
    const float t = __builtin_amdgcn_exp2f(TL2 * x);
    return 1.0f - 2.0f / (t + 1.0f) * 1.0f;
}

__device__ __forceinline__ unsigned short f2bs(float x) {
    __hip_bfloat16 b = __float2bfloat16(x);
    return __builtin_bit_cast(unsigned short, b);
}

__device__ __forceinline__ float bs2f(unsigned short u) {
    return __builtin_bit_cast(float, ((unsigned)u) << 16);
}

// Inline weight-fragment loaders (replace the old k_prep kernel): convert
// f32 weights to bf16 MFMA B-fragments on the fly (RNE, identical values).
// Strided gather: B[j] = W[(k0+j)*64 + n]; clamp k to kmax (clamped rows
// multiply zero-padded A entries or feed discarded columns -> finite, safe).
__device__ __forceinline__ frag_ab ldw_strided(const float* __restrict__ W,
                                               int k0, int n, int kmax) {
    frag_ab r;
#pragma unroll
    for (int j = 0; j < 8; j++) {
        int k = k0 + j;
        if (k > kmax) k = kmax;
        r[j] = (short)f2bs(W[k * 64 + n]);
    }
    return r;
}
__device__ __forceinline__ frag_ab ldw_contig(const float* __restrict__ W,
                                              int off) {
    const f4 a = *(const f4*)&W[off];
    const f4 b = *(const f4*)&W[off + 4];
    frag_ab r;
    r[0] = (short)f2bs(a.x); r[1] = (short)f2bs(a.y);
    r[2] = (short)f2bs(a.z); r[3] = (short)f2bs(a.w);
    r[4] = (short)f2bs(b.x); r[5] = (short)f2bs(b.y);
    r[6] = (short)f2bs(b.z); r[7] = (short)f2bs(b.w);
    return r;
}

// DPP cross-lane add. 0xB1/0x4E = quad_perm xor1/xor2 (butterfly).
// 0x110|s = row_shr s (16-lane sum lands in lane 15 of each DPP row).
template <int CTRL>
__device__ __forceinline__ float dpp_add(float x) {
    const int y = __builtin_amdgcn_update_dpp(
        0, __builtin_bit_cast(int, x), CTRL, 0xF, 0xF, true);
    return x + __builtin_bit_cast(float, y);
}

// ---------------- Fused kernel: block = 1 atom (48 pairs), 4 waves --------
// Single-launch variant of the best (R7) structure: k_prep folded in as
// inline f32->bf16 fragment conversion (L2/L3-hot weight reads, hidden
// under ph0/ph1). LDS layout identical to R3/R7 (20,448 B):
//  A @0     (6912): h1S [48][72]s16 (fwd/bwd) | sT bf16 [48][49] (8b-8c)
//  B @6912  (6912): descS [48][40]s16 | sgd [48][19]f32 + sgf4 + sgu4
//  C @13824 (4704): sS bf16 [48][49]
//  SE @18528 (768), SU @19296 (768), SFC @20064 (192), SFK @20256 (192)
#define H1_OFF   0
#define ST_OFF   0
#define DESC_OFF 6912
#define GZ2_OFF  6912
#define SGD_OFF  6912
#define SGF_OFF  10560
#define SGU_OFF  11328
#define SS_OFF   13824
#define SE_OFF   18528
#define SU_OFF   19296
#define SFC_OFF  20064
#define SFK_OFF  20256
#define SM_BYTES 20448

__global__ __launch_bounds__(256, 6) void k_fused(const float* __restrict__ rij,
                                                  const float* __restrict__ W1,
                                                  const float* __restrict__ b1,
                                                  const float* __restrict__ W2,
                                                  const float* __restrict__ b2,
                                                  const float* __restrict__ W3,
                                                  const float* __restrict__ b3,
                                                  float* __restrict__ out) {
    __shared__ __align__(16) char smem[SM_BYTES];
    short*          h1S   = (short*)(smem + H1_OFF);           // [row*72+n]
    unsigned short* sT    = (unsigned short*)(smem + ST_OFF);  // [k*49+l] bf16
    short*          descS = (short*)(smem + DESC_OFF);         // [row*40+j]
    short*          gz2S  = (short*)(smem + GZ2_OFF);          // [row*72+n]
    float*          sgd   = (float*)(smem + SGD_OFF);          // [k*19+{0..16,17:eij}]
    float*          sgf4  = (float*)(smem + SGF_OFF);          // [w*48+l]
    float*          sgu4  = (float*)(smem + SGU_OFF);          // [(w*48+k)*3+c]
    unsigned short* sS    = (unsigned short*)(smem + SS_OFF);  // [k*49+l] bf16
    float*          se    = (float*)(smem + SE_OFF);           // [w*48+row]
    float*          su    = (float*)(smem + SU_OFF);           // [4k+{x,y,z,d}]
    float*          sfc   = (float*)(smem + SFC_OFF);
    float*          sfk   = (float*)(smem + SFK_OFF);

    const int t = threadIdx.x;
    const int base3 = blockIdx.x * (K * 3);
    const int w = t >> 6, lane = t & 63, quad = lane >> 4, lm = lane & 15;
    const int n0 = w * 16 + lm;

    // per-wave fixed MFMA B-fragments (converted inline from f32; these
    // global reads are L2/L3-hot and hide under ph0/ph1)
    const frag_ab wf1  = ldw_strided(W1, quad * 8, n0, 16);        // W1T[n0][k]
    const frag_ab wf2a = ldw_strided(W2, quad * 8, n0, 63);        // W2T[n0][k]
    const frag_ab wf2b = ldw_strided(W2, 32 + quad * 8, n0, 63);
    const frag_ab wr2a = ldw_contig(W2, n0 * 64 + quad * 8);       // W2R[n0][k]
    const frag_ab wr2b = ldw_contig(W2, n0 * 64 + 32 + quad * 8);
    const float bias1 = b1[n0];
    const float bias2 = b2[n0];
    const float w3n   = W3[n0];
    const float b3v   = b3[0];

    // ---- phase 0: geometry + rbf (sin/cos recurrence) + K-pad ----
    if (t < K) {
        const float x = rij[base3 + 3 * t];
        const float y = rij[base3 + 3 * t + 1];
        const float z = rij[base3 + 3 * t + 2];
        float s2 = fmaxf(x * x + y * y + z * z, 1e-24f);
        const float inv = __builtin_amdgcn_rsqf(s2);
        const float d = s2 * inv;
        *(f4*)&su[4 * t] = (f4){x * inv, y * inv, z * inv, d};
        sfk[t] = 0.5f + 0.5f * __cosf(POC * d);
        const float fc = (d > RMIN_F) ? (0.5f + 0.5f * __cosf(AFC * (d - RMIN_F))) : 1.0f;
        sfc[t] = fc;
        float s1, c1;
        __sincosf(POC * d, &s1, &c1);
        const float sc = SQ * fc * inv;
        float sn = s1, cn = c1;
#pragma unroll 1
        for (int n = 0; n < NR; n++) {
            descS[t * 40 + n] = (short)f2bs(sc * sn);
            const float snx = sn * c1 + cn * s1;
            cn = cn * c1 - sn * s1;
            sn = snx;
        }
#pragma unroll 1
        for (int c = ND; c < 32; c++) descS[t * 40 + c] = 0;  // K-pad
    }
    __syncthreads();   // B1

    // ---- phase 1: 3-body descriptors (t = 4k+ch, DPP quad-reduced) ----
    if (t < 192) {
        const int k = t >> 2, ch = t & 3;
        const f4 uk = *(const f4*)&su[4 * k];
        const float* sul = &su[4 * (ch * 12)];
        f2 partv[6];
#pragma unroll
        for (int i = 0; i < 6; i++) partv[i] = (f2){0.0f, 0.0f};
#pragma unroll 1
        for (int li = 0; li < 12; li++) {
            const int l = ch * 12 + li;
            const f4 ul = *(const f4*)&sul[4 * li];
            float c = uk.x * ul.x + uk.y * ul.y + uk.z * ul.z;
            if (k == l) c = 0.0f;
            const float cp1 = c + 1.0f;
            const float e0 = __builtin_amdgcn_exp2f(N4L * cp1 * cp1) * sfk[l];
            const float e1 = __builtin_amdgcn_exp2f(E1L * cp1);
            const float e2s = e1 * e1;
            const f2 e2v = {e2s, e2s};
            f2 tm = {e0, e0 * e1};
            partv[0] += tm;
#pragma unroll
            for (int i = 1; i < 6; i++) { tm *= e2v; partv[i] += tm; }
        }
#pragma unroll
        for (int i = 0; i < 6; i++) {
            partv[i].x = dpp_add<0x4E>(dpp_add<0xB1>(partv[i].x));
            partv[i].y = dpp_add<0x4E>(dpp_add<0xB1>(partv[i].y));
        }
        if (ch == 0) {
#pragma unroll
            for (int i = 0; i < 6; i++) {
                const int m0 = 2 * i, m1 = 2 * i + 1;
                descS[k * 40 + NR + m0] =
                    (short)f2bs(partv[i].x * __expf(CMC * (float)(m0 * m0)));
                descS[k * 40 + NR + m1] =
                    (short)f2bs(partv[i].y * __expf(CMC * (float)(m1 * m1)));
            }
        }
    }
    __syncthreads();   // B2

    // ---- fwd1: h1 = tanh(desc @ W1 + b1)  (N-split: wave w owns cols n0) ----
#pragma unroll 1
    for (int mt = 0; mt < 3; mt++) {
        const frag_ab a = *(const frag_ab*)&descS[(mt * 16 + lm) * 40 + quad * 8];
        frag_cd acc = {bias1, bias1, bias1, bias1};
        acc = __builtin_amdgcn_mfma_f32_16x16x32_bf16(a, wf1, acc, 0, 0, 0);
#pragma unroll
        for (int r = 0; r < 4; r++)
            h1S[(mt * 16 + quad * 4 + r) * 72 + n0] = (short)f2bs(fast_tanh(acc[r]));
    }
    __syncthreads();   // B3

    // ---- fwd2: t2 = tanh(h1@W2+b2); eij row-sums -> se; gz2 ----
#pragma unroll 1
    for (int mt = 0; mt < 3; mt++) {
        const frag_ab a0 = *(const frag_ab*)&h1S[(mt * 16 + lm) * 72 + quad * 8];
        const frag_ab a1 = *(const frag_ab*)&h1S[(mt * 16 + lm) * 72 + 32 + quad * 8];
        frag_cd acc = {bias2, bias2, bias2, bias2};
        acc = __builtin_amdgcn_mfma_f32_16x16x32_bf16(a0, wf2a, acc, 0, 0, 0);
        acc = __builtin_amdgcn_mfma_f32_16x16x32_bf16(a1, wf2b, acc, 0, 0, 0);
        float ep[4];
#pragma unroll
        for (int r = 0; r < 4; r++) {
            const int row = mt * 16 + quad * 4 + r;
            const float tv = fast_tanh(acc[r]);
            ep[r] = tv * w3n;
            gz2S[row * 72 + n0] = (short)f2bs(sfc[row] * w3n * (1.0f - tv * tv));
        }
#pragma unroll
        for (int r = 0; r < 4; r++)
            ep[r] = dpp_add<0x118>(dpp_add<0x114>(dpp_add<0x112>(dpp_add<0x111>(ep[r]))));
        if (lm == 15) {
#pragma unroll
            for (int r = 0; r < 4; r++) se[w * 48 + mt * 16 + quad * 4 + r] = ep[r];
        }
    }
    __syncthreads();   // B4

    // ---- bwd1: gz1 = (gz2 @ W2^T)*(1-t1^2); t1 re-read from h1S (bf16) ----
#pragma unroll 1
    for (int mt = 0; mt < 3; mt++) {
        const frag_ab a0 = *(const frag_ab*)&gz2S[(mt * 16 + lm) * 72 + quad * 8];
        const frag_ab a1 = *(const frag_ab*)&gz2S[(mt * 16 + lm) * 72 + 32 + quad * 8];
        frag_cd acc = {0.0f, 0.0f, 0.0f, 0.0f};
        acc = __builtin_amdgcn_mfma_f32_16x16x32_bf16(a0, wr2a, acc, 0, 0, 0);
        acc = __builtin_amdgcn_mfma_f32_16x16x32_bf16(a1, wr2b, acc, 0, 0, 0);
#pragma unroll
        for (int r = 0; r < 4; r++) {
            const int row = mt * 16 + quad * 4 + r;
            const float tv = bs2f((unsigned short)h1S[row * 72 + n0]);
            h1S[row * 72 + n0] = (short)f2bs(acc[r] * (1.0f - tv * tv));
        }
    }
    __syncthreads();   // B5

    // ---- bwd2: gdesc = gz1 @ W1^T -> sgd (C_m pre-scaled); eij -> sgd ----
#pragma unroll 1
    for (int tid = w; tid < 6; tid += 4) {
        const int mt = tid >> 1, nt = tid & 1, n = nt * 16 + lm;
        const int nc = (n < ND) ? n : 16;    // clamp: cols >=17 discarded below
        const frag_ab b0 = ldw_contig(W1, nc * 64 + quad * 8);
        const frag_ab b1f = ldw_contig(W1, nc * 64 + 32 + quad * 8);
        const frag_ab a0 = *(const frag_ab*)&h1S[(mt * 16 + lm) * 72 + quad * 8];
        const frag_ab a1 = *(const frag_ab*)&h1S[(mt * 16 + lm) * 72 + 32 + quad * 8];
        frag_cd acc = {0.0f, 0.0f, 0.0f, 0.0f};
        acc = __builtin_amdgcn_mfma_f32_16x16x32_bf16(a0, b0, acc, 0, 0, 0);
        acc = __builtin_amdgcn_mfma_f32_16x16x32_bf16(a1, b1f, acc, 0, 0, 0);
        if (n < ND) {
            const int mm = n - NR;
            const float cmul = (n >= NR) ? __expf(CMC * (float)(mm * mm)) : 1.0f;
#pragma unroll
            for (int r = 0; r < 4; r++)
                sgd[(mt * 16 + quad * 4 + r) * 19 + n] = acc[r] * cmul;
        }
    }
    if (t < K)
        sgd[t * 19 + 17] = se[t] + se[48 + t] + se[96 + t] + se[144 + t] + b3v;
    __syncthreads();   // B6

    // ---- 8b: recompute cos; dual Horner; S,T -> LDS (bf16) ----
    if (t < 192) {
        const int k = t >> 2, ch = t & 3;
        f2 gm[NM];
#pragma unroll
        for (int m = 0; m < NM; m++) {
            const float g = sgd[k * 19 + NR + m];
            gm[m] = (f2){g, (float)m * g};
        }
        const f4 uk = *(const f4*)&su[4 * k];
        const float* sul = &su[4 * (ch * 12)];
#pragma unroll 1
        for (int li = 0; li < 12; li++) {
            const int l = ch * 12 + li;
            const f4 ul = *(const f4*)&sul[4 * li];
            float c = uk.x * ul.x + uk.y * ul.y + uk.z * ul.z;
            if (k == l) c = 0.0f;
            const float cp1 = c + 1.0f;
            const float e0 = __builtin_amdgcn_exp2f(N4L * cp1 * cp1);
            const float x = __builtin_amdgcn_exp2f(E1L * cp1);
            const f2 xx = {x, x};
            f2 pd = gm[11];
#pragma unroll
            for (int m = 10; m >= 1; m--) pd = __builtin_elementwise_fma(pd, xx, gm[m]);
            const float Pv = fmaf(pd.x, x, gm[0].x);
            const float T = e0 * Pv;
            const float U = e0 * x * pd.y;
            const float Sp = fmaf(cp1, T, -(2.0f / 11.0f) * U);
            const float Sv = (k == l) ? 0.0f : (-8.0f) * Sp;
            sT[k * 49 + l] = f2bs(T);
            sS[k * 49 + l] = f2bs(Sv);
        }
    }
    __syncthreads();   // B7

    // ---- 8c: partial column reductions, all 4 waves ----
    if (lane < K) {
        float s = 0.0f;
#pragma unroll 1
        for (int kk = 12 * w; kk < 12 * w + 12; kk++) s += bs2f(sT[kk * 49 + lane]);
        sgf4[w * 48 + lane] = s;

        const int k = lane;
        const float fk = sfk[k];
        float gx = 0.0f, gy = 0.0f, gz = 0.0f;
#pragma unroll 1
        for (int l = 12 * w; l < 12 * w + 12; l++) {
            const float wgt = fmaf(bs2f(sS[k * 49 + l]), sfk[l],
                                   bs2f(sS[l * 49 + k]) * fk);
            const f4 ul = *(const f4*)&su[4 * l];
            gx = fmaf(wgt, ul.x, gx);
            gy = fmaf(wgt, ul.y, gy);
            gz = fmaf(wgt, ul.z, gz);
        }
        sgu4[(w * 48 + k) * 3 + 0] = gx;
        sgu4[(w * 48 + k) * 3 + 1] = gy;
        sgu4[(w * 48 + k) * 3 + 2] = gz;
    }
    __syncthreads();   // B8

    // ---- 8d: combine partials, assemble gradient, write out ----
    if (t < K) {
        const float sgf_t = sgf4[t] + sgf4[48 + t] + sgf4[96 + t] + sgf4[144 + t];
        float gux = 0.0f, guy = 0.0f, guz = 0.0f;
#pragma unroll
        for (int ww = 0; ww < 4; ww++) {
            gux += sgu4[(ww * 48 + t) * 3 + 0];
            guy += sgu4[(ww * 48 + t) * 3 + 1];
            guz += sgu4[(ww * 48 + t) * 3 + 2];
        }
        const f4 uv = *(const f4*)&su[4 * t];
        const float d = uv.w;
        const float ux = uv.x, uy = uv.y, uz = uv.z;
        const float invd = __builtin_amdgcn_rcpf(d);
        float gfc = sgd[t * 19 + 17];
        float gdR = 0.0f;
        float s1, c1;
        __sincosf(POC * d, &s1, &c1);
        float sn = s1, cn = c1, bn = POC;
#pragma unroll 1
        for (int n = 0; n < NR; n++) {
            const float g = sgd[t * 19 + n];
            gfc = fmaf(g, SQ * sn * invd, gfc);
            gdR = fmaf(g, SQ * (bn * cn - sn * invd) * invd, gdR);
            const float snx = sn * c1 + cn * s1;
            cn = cn * c1 - sn * s1;
            sn = snx;
            bn += POC;
        }
        const float fc = sfc[t];
        float dfc = 0.0f;
        if (d > RMIN_F) dfc = -0.5f * AFC * __sinf(AFC * (d - RMIN_F));
        const float dfcrik = -0.5f * POC * __sinf(POC * d);

        const float gd = fc * gdR + gfc * dfc + sgf_t * dfcrik;
        const float dot = gux * ux + guy * uy + guz * uz;

        out[base3 + 3 * t + 0] = fmaf(gd, ux, (gux - dot * ux) * invd);
        out[base3 + 3 * t + 1] = fmaf(gd, uy, (guy - dot * uy) * invd);
        out[base3 + 3 * t + 2] = fmaf(gd, uz, (guz - dot * uz) * invd);
    }
}

extern "C" void kernel_launch(void* const* d_in, const int* in_sizes, int n_in,
                              void* d_out, int out_size, void* d_ws, size_t ws_size,
                              hipStream_t stream) {
    (void)in_sizes; (void)n_in; (void)out_size; (void)d_ws; (void)ws_size;
    const float* rij = (const float*)d_in[0];
    // d_in[1] = unique_i (unused: dense K neighbors per atom)
    const float* W1 = (const float*)d_in[2];
    const float* b1 = (const float*)d_in[3];
    const float* W2 = (const float*)d_in[4];
    const float* b2 = (const float*)d_in[5];
    const float* W3 = (const float*)d_in[6];
    const float* b3 = (const float*)d_in[7];
    float* out = (float*)d_out;

    k_fused<<<NATOMS, 256, 0, stream>>>(rij, W1, b1, W2, b2, W3, b3, out);
}

// Round 11
// 94.367 us; speedup vs baseline: 1.0628x; 1.0117x over previous
//
#include <hip/hip_runtime.h>
#include <hip/hip_bf16.h>

#define NATOMS 2048
#define K 48
#define NR 5
#define NM 12
#define ND 17
#define HID 64

#define PI_F 3.14159265358979f
#define CUT 3.0f
#define RMIN_F 3.5f
#define AFC (-6.28318530717959f)   /* pi/(CUT-RMIN) = pi/(-0.5) */
#define POC (PI_F / CUT)           /* pi/3 */
#define SQ 0.816496580927726f      /* sqrt(2/3) */
#define CMC (-0.132231404958678f)  /* -16/121 */
/* exp2-folded constants (x * log2(e)) */
#define N4L (-5.77078016355585f)   /* -4 * log2e */
#define E1L (2.09846551402031f)    /* (16/11) * log2e */
#define TL2 (2.88539008177793f)    /* 2 * log2e */

// Packed bf16 weight layouts (built once per launch by k_prep).
__device__ unsigned short g_w1t[64 * 32];  // [n=h][k=j]  (k>=17 zero)
__device__ unsigned short g_w2t[64 * 64];  // [n=h2][k=h1]
__device__ unsigned short g_w2r[64 * 64];  // [n=h1][k=h2]
__device__ unsigned short g_w1r[32 * 64];  // [n=j][k=h]  (n>=17 zero)

using frag_ab = __attribute__((ext_vector_type(8))) short;
using frag_cd = __attribute__((ext_vector_type(4))) float;
using f2 = __attribute__((ext_vector_type(2))) float;
using f4 = __attribute__((ext_vector_type(4))) float;

__device__ __forceinline__ float fast_tanh(float x) {
    const float t = __builtin_amdgcn_exp2f(TL2 * x);
    return 1.0f - 2.0f * __builtin_amdgcn_rcpf(t + 1.0f);
}

__device__ __forceinline__ unsigned short f2bs(float x) {
    __hip_bfloat16 b = __float2bfloat16(x);
    return __builtin_bit_cast(unsigned short, b);
}

__device__ __forceinline__ float bs2f(unsigned short u) {
    return __builtin_bit_cast(float, ((unsigned)u) << 16);
}

// DPP cross-lane add. 0xB1/0x4E = quad_perm xor1/xor2 (butterfly).
// 0x110|s = row_shr s (16-lane sum lands in lane 15 of each DPP row).
template <int CTRL>
__device__ __forceinline__ float dpp_add(float x) {
    const int y = __builtin_amdgcn_update_dpp(
        0, __builtin_bit_cast(int, x), CTRL, 0xF, 0xF, true);
    return x + __builtin_bit_cast(float, y);
}

// ---------------- Kernel 0: pack weights into MFMA-ready bf16 layouts -----
__global__ __launch_bounds__(256) void k_prep(const float* __restrict__ W1,
                                              const float* __restrict__ W2) {
    const int i = blockIdx.x * 256 + threadIdx.x;  // grid covers 12288
    if (i < 2048) {                                   // W1T[n][k]
        const int n = i >> 5, k = i & 31;
        g_w1t[i] = (k < ND) ? f2bs(W1[k * HID + n]) : (unsigned short)0;
    } else if (i < 2048 + 4096) {                     // W2T[n][k]
        const int j = i - 2048, n = j >> 6, k = j & 63;
        g_w2t[j] = f2bs(W2[k * HID + n]);
    } else if (i < 2048 + 8192) {                     // W2R[n][k]
        const int j = i - (2048 + 4096);
        g_w2r[j] = f2bs(W2[j]);
    } else if (i < 2048 + 8192 + 2048) {              // W1R[n][k]
        const int j = i - (2048 + 8192), n = j >> 6;
        g_w1r[j] = (n < ND) ? f2bs(W1[j]) : (unsigned short)0;
    }
}

// ---------------- Fused kernel: block = 1 atom (48 pairs), 4 waves --------
// Best-measured configuration (R7, 92.62 us): rolled loops (small I$
// footprint), DPP reductions, hoisted weight fragments, sin/cos
// recurrences, bf16 S/T, 20,448 B LDS.
//  A @0     (6912): h1S [48][72]s16 (fwd/bwd) | sT bf16 [48][49] (8b-8c)
//  B @6912  (6912): descS [48][40]s16 | sgd [48][19]f32 + sgf4 + sgu4
//  C @13824 (4704): sS bf16 [48][49]
//  SE @18528 (768), SU @19296 (768), SFC @20064 (192), SFK @20256 (192)
#define H1_OFF   0
#define ST_OFF   0
#define DESC_OFF 6912
#define GZ2_OFF  6912
#define SGD_OFF  6912
#define SGF_OFF  10560
#define SGU_OFF  11328
#define SS_OFF   13824
#define SE_OFF   18528
#define SU_OFF   19296
#define SFC_OFF  20064
#define SFK_OFF  20256
#define SM_BYTES 20448

__global__ __launch_bounds__(256, 6) void k_fused(const float* __restrict__ rij,
                                                  const float* __restrict__ b1,
                                                  const float* __restrict__ b2,
                                                  const float* __restrict__ W3,
                                                  const float* __restrict__ b3,
                                                  float* __restrict__ out) {
    __shared__ __align__(16) char smem[SM_BYTES];
    short*          h1S   = (short*)(smem + H1_OFF);           // [row*72+n]
    unsigned short* sT    = (unsigned short*)(smem + ST_OFF);  // [k*49+l] bf16
    short*          descS = (short*)(smem + DESC_OFF);         // [row*40+j]
    short*          gz2S  = (short*)(smem + GZ2_OFF);          // [row*72+n]
    float*          sgd   = (float*)(smem + SGD_OFF);          // [k*19+{0..16,17:eij}]
    float*          sgf4  = (float*)(smem + SGF_OFF);          // [w*48+l]
    float*          sgu4  = (float*)(smem + SGU_OFF);          // [(w*48+k)*3+c]
    unsigned short* sS    = (unsigned short*)(smem + SS_OFF);  // [k*49+l] bf16
    float*          se    = (float*)(smem + SE_OFF);           // [w*48+row]
    float*          su    = (float*)(smem + SU_OFF);           // [4k+{x,y,z,d}]
    float*          sfc   = (float*)(smem + SFC_OFF);
    float*          sfk   = (float*)(smem + SFK_OFF);

    const int t = threadIdx.x;
    const int base3 = blockIdx.x * (K * 3);
    const int w = t >> 6, lane = t & 63, quad = lane >> 4, lm = lane & 15;
    const int n0 = w * 16 + lm;

    // per-wave fixed MFMA B-fragments (one N-tile per wave) + scalars
    const frag_ab wf1  = *(const frag_ab*)&g_w1t[n0 * 32 + quad * 8];
    const frag_ab wf2a = *(const frag_ab*)&g_w2t[n0 * 64 + quad * 8];
    const frag_ab wf2b = *(const frag_ab*)&g_w2t[n0 * 64 + 32 + quad * 8];
    const frag_ab wr2a = *(const frag_ab*)&g_w2r[n0 * 64 + quad * 8];
    const frag_ab wr2b = *(const frag_ab*)&g_w2r[n0 * 64 + 32 + quad * 8];
    const float bias1 = b1[n0];
    const float bias2 = b2[n0];
    const float w3n   = W3[n0];
    const float b3v   = b3[0];

    // ---- phase 0: geometry + rbf (sin/cos recurrence) + K-pad ----
    if (t < K) {
        const float x = rij[base3 + 3 * t];
        const float y = rij[base3 + 3 * t + 1];
        const float z = rij[base3 + 3 * t + 2];
        float s2 = fmaxf(x * x + y * y + z * z, 1e-24f);
        const float inv = __builtin_amdgcn_rsqf(s2);
        const float d = s2 * inv;
        *(f4*)&su[4 * t] = (f4){x * inv, y * inv, z * inv, d};
        sfk[t] = 0.5f + 0.5f * __cosf(POC * d);
        const float fc = (d > RMIN_F) ? (0.5f + 0.5f * __cosf(AFC * (d - RMIN_F))) : 1.0f;
        sfc[t] = fc;
        float s1, c1;
        __sincosf(POC * d, &s1, &c1);
        const float sc = SQ * fc * inv;
        float sn = s1, cn = c1;
#pragma unroll 1
        for (int n = 0; n < NR; n++) {
            descS[t * 40 + n] = (short)f2bs(sc * sn);
            const float snx = sn * c1 + cn * s1;
            cn = cn * c1 - sn * s1;
            sn = snx;
        }
#pragma unroll 1
        for (int c = ND; c < 32; c++) descS[t * 40 + c] = 0;  // K-pad
    }
    __syncthreads();   // B1

    // ---- phase 1: 3-body descriptors (t = 4k+ch, DPP quad-reduced) ----
    if (t < 192) {
        const int k = t >> 2, ch = t & 3;
        const f4 uk = *(const f4*)&su[4 * k];
        const float* sul = &su[4 * (ch * 12)];
        f2 partv[6];
#pragma unroll
        for (int i = 0; i < 6; i++) partv[i] = (f2){0.0f, 0.0f};
#pragma unroll 1
        for (int li = 0; li < 12; li++) {
            const int l = ch * 12 + li;
            const f4 ul = *(const f4*)&sul[4 * li];
            float c = uk.x * ul.x + uk.y * ul.y + uk.z * ul.z;
            if (k == l) c = 0.0f;
            const float cp1 = c + 1.0f;
            const float e0 = __builtin_amdgcn_exp2f(N4L * cp1 * cp1) * sfk[l];
            const float e1 = __builtin_amdgcn_exp2f(E1L * cp1);
            const float e2s = e1 * e1;
            const f2 e2v = {e2s, e2s};
            f2 tm = {e0, e0 * e1};
            partv[0] += tm;
#pragma unroll
            for (int i = 1; i < 6; i++) { tm *= e2v; partv[i] += tm; }
        }
#pragma unroll
        for (int i = 0; i < 6; i++) {
            partv[i].x = dpp_add<0x4E>(dpp_add<0xB1>(partv[i].x));
            partv[i].y = dpp_add<0x4E>(dpp_add<0xB1>(partv[i].y));
        }
        if (ch == 0) {
#pragma unroll
            for (int i = 0; i < 6; i++) {
                const int m0 = 2 * i, m1 = 2 * i + 1;
                descS[k * 40 + NR + m0] =
                    (short)f2bs(partv[i].x * __expf(CMC * (float)(m0 * m0)));
                descS[k * 40 + NR + m1] =
                    (short)f2bs(partv[i].y * __expf(CMC * (float)(m1 * m1)));
            }
        }
    }
    __syncthreads();   // B2

    // ---- fwd1: h1 = tanh(desc @ W1 + b1)  (N-split: wave w owns cols n0) ----
#pragma unroll 1
    for (int mt = 0; mt < 3; mt++) {
        const frag_ab a = *(const frag_ab*)&descS[(mt * 16 + lm) * 40 + quad * 8];
        frag_cd acc = {bias1, bias1, bias1, bias1};
        acc = __builtin_amdgcn_mfma_f32_16x16x32_bf16(a, wf1, acc, 0, 0, 0);
#pragma unroll
        for (int r = 0; r < 4; r++)
            h1S[(mt * 16 + quad * 4 + r) * 72 + n0] = (short)f2bs(fast_tanh(acc[r]));
    }
    __syncthreads();   // B3

    // ---- fwd2: t2 = tanh(h1@W2+b2); eij row-sums -> se; gz2 ----
#pragma unroll 1
    for (int mt = 0; mt < 3; mt++) {
        const frag_ab a0 = *(const frag_ab*)&h1S[(mt * 16 + lm) * 72 + quad * 8];
        const frag_ab a1 = *(const frag_ab*)&h1S[(mt * 16 + lm) * 72 + 32 + quad * 8];
        frag_cd acc = {bias2, bias2, bias2, bias2};
        acc = __builtin_amdgcn_mfma_f32_16x16x32_bf16(a0, wf2a, acc, 0, 0, 0);
        acc = __builtin_amdgcn_mfma_f32_16x16x32_bf16(a1, wf2b, acc, 0, 0, 0);
        float ep[4];
#pragma unroll
        for (int r = 0; r < 4; r++) {
            const int row = mt * 16 + quad * 4 + r;
            const float tv = fast_tanh(acc[r]);
            ep[r] = tv * w3n;
            gz2S[row * 72 + n0] = (short)f2bs(sfc[row] * w3n * (1.0f - tv * tv));
        }
#pragma unroll
        for (int r = 0; r < 4; r++)
            ep[r] = dpp_add<0x118>(dpp_add<0x114>(dpp_add<0x112>(dpp_add<0x111>(ep[r]))));
        if (lm == 15) {
#pragma unroll
            for (int r = 0; r < 4; r++) se[w * 48 + mt * 16 + quad * 4 + r] = ep[r];
        }
    }
    __syncthreads();   // B4

    // ---- bwd1: gz1 = (gz2 @ W2^T)*(1-t1^2); t1 re-read from h1S (bf16) ----
#pragma unroll 1
    for (int mt = 0; mt < 3; mt++) {
        const frag_ab a0 = *(const frag_ab*)&gz2S[(mt * 16 + lm) * 72 + quad * 8];
        const frag_ab a1 = *(const frag_ab*)&gz2S[(mt * 16 + lm) * 72 + 32 + quad * 8];
        frag_cd acc = {0.0f, 0.0f, 0.0f, 0.0f};
        acc = __builtin_amdgcn_mfma_f32_16x16x32_bf16(a0, wr2a, acc, 0, 0, 0);
        acc = __builtin_amdgcn_mfma_f32_16x16x32_bf16(a1, wr2b, acc, 0, 0, 0);
#pragma unroll
        for (int r = 0; r < 4; r++) {
            const int row = mt * 16 + quad * 4 + r;
            const float tv = bs2f((unsigned short)h1S[row * 72 + n0]);
            h1S[row * 72 + n0] = (short)f2bs(acc[r] * (1.0f - tv * tv));
        }
    }
    __syncthreads();   // B5

    // ---- bwd2: gdesc = gz1 @ W1^T -> sgd (C_m pre-scaled); eij -> sgd ----
#pragma unroll 1
    for (int tid = w; tid < 6; tid += 4) {
        const int mt = tid >> 1, nt = tid & 1, n = nt * 16 + lm;
        const frag_ab b0 = *(const frag_ab*)&g_w1r[n * 64 + quad * 8];
        const frag_ab b1f = *(const frag_ab*)&g_w1r[n * 64 + 32 + quad * 8];
        const frag_ab a0 = *(const frag_ab*)&h1S[(mt * 16 + lm) * 72 + quad * 8];
        const frag_ab a1 = *(const frag_ab*)&h1S[(mt * 16 + lm) * 72 + 32 + quad * 8];
        frag_cd acc = {0.0f, 0.0f, 0.0f, 0.0f};
        acc = __builtin_amdgcn_mfma_f32_16x16x32_bf16(a0, b0, acc, 0, 0, 0);
        acc = __builtin_amdgcn_mfma_f32_16x16x32_bf16(a1, b1f, acc, 0, 0, 0);
        if (n < ND) {
            const int mm = n - NR;
            const float cmul = (n >= NR) ? __expf(CMC * (float)(mm * mm)) : 1.0f;
#pragma unroll
            for (int r = 0; r < 4; r++)
                sgd[(mt * 16 + quad * 4 + r) * 19 + n] = acc[r] * cmul;
        }
    }
    if (t < K)
        sgd[t * 19 + 17] = se[t] + se[48 + t] + se[96 + t] + se[144 + t] + b3v;
    __syncthreads();   // B6

    // ---- 8b: recompute cos; dual Horner; S,T -> LDS (bf16) ----
    if (t < 192) {
        const int k = t >> 2, ch = t & 3;
        f2 gm[NM];
#pragma unroll
        for (int m = 0; m < NM; m++) {
            const float g = sgd[k * 19 + NR + m];
            gm[m] = (f2){g, (float)m * g};
        }
        const f4 uk = *(const f4*)&su[4 * k];
        const float* sul = &su[4 * (ch * 12)];
#pragma unroll 1
        for (int li = 0; li < 12; li++) {
            const int l = ch * 12 + li;
            const f4 ul = *(const f4*)&sul[4 * li];
            float c = uk.x * ul.x + uk.y * ul.y + uk.z * ul.z;
            if (k == l) c = 0.0f;
            const float cp1 = c + 1.0f;
            const float e0 = __builtin_amdgcn_exp2f(N4L * cp1 * cp1);
            const float x = __builtin_amdgcn_exp2f(E1L * cp1);
            const f2 xx = {x, x};
            f2 pd = gm[11];
#pragma unroll
            for (int m = 10; m >= 1; m--) pd = __builtin_elementwise_fma(pd, xx, gm[m]);
            const float Pv = fmaf(pd.x, x, gm[0].x);
            const float T = e0 * Pv;
            const float U = e0 * x * pd.y;
            const float Sp = fmaf(cp1, T, -(2.0f / 11.0f) * U);
            const float Sv = (k == l) ? 0.0f : (-8.0f) * Sp;
            sT[k * 49 + l] = f2bs(T);
            sS[k * 49 + l] = f2bs(Sv);
        }
    }
    __syncthreads();   // B7

    // ---- 8c: partial column reductions, all 4 waves ----
    if (lane < K) {
        float s = 0.0f;
#pragma unroll 1
        for (int kk = 12 * w; kk < 12 * w + 12; kk++) s += bs2f(sT[kk * 49 + lane]);
        sgf4[w * 48 + lane] = s;

        const int k = lane;
        const float fk = sfk[k];
        float gx = 0.0f, gy = 0.0f, gz = 0.0f;
#pragma unroll 1
        for (int l = 12 * w; l < 12 * w + 12; l++) {
            const float wgt = fmaf(bs2f(sS[k * 49 + l]), sfk[l],
                                   bs2f(sS[l * 49 + k]) * fk);
            const f4 ul = *(const f4*)&su[4 * l];
            gx = fmaf(wgt, ul.x, gx);
            gy = fmaf(wgt, ul.y, gy);
            gz = fmaf(wgt, ul.z, gz);
        }
        sgu4[(w * 48 + k) * 3 + 0] = gx;
        sgu4[(w * 48 + k) * 3 + 1] = gy;
        sgu4[(w * 48 + k) * 3 + 2] = gz;
    }
    __syncthreads();   // B8

    // ---- 8d: combine partials, assemble gradient, write out ----
    if (t < K) {
        const float sgf_t = sgf4[t] + sgf4[48 + t] + sgf4[96 + t] + sgf4[144 + t];
        float gux = 0.0f, guy = 0.0f, guz = 0.0f;
#pragma unroll
        for (int ww = 0; ww < 4; ww++) {
            gux += sgu4[(ww * 48 + t) * 3 + 0];
            guy += sgu4[(ww * 48 + t) * 3 + 1];
            guz += sgu4[(ww * 48 + t) * 3 + 2];
        }
        const f4 uv = *(const f4*)&su[4 * t];
        const float d = uv.w;
        const float ux = uv.x, uy = uv.y, uz = uv.z;
        const float invd = __builtin_amdgcn_rcpf(d);
        float gfc = sgd[t * 19 + 17];
        float gdR = 0.0f;
        float s1, c1;
        __sincosf(POC * d, &s1, &c1);
        float sn = s1, cn = c1, bn = POC;
#pragma unroll 1
        for (int n = 0; n < NR; n++) {
            const float g = sgd[t * 19 + n];
            gfc = fmaf(g, SQ * sn * invd, gfc);
            gdR = fmaf(g, SQ * (bn * cn - sn * invd) * invd, gdR);
            const float snx = sn * c1 + cn * s1;
            cn = cn * c1 - sn * s1;
            sn = snx;
            bn += POC;
        }
        const float fc = sfc[t];
        float dfc = 0.0f;
        if (d > RMIN_F) dfc = -0.5f * AFC * __sinf(AFC * (d - RMIN_F));
        const float dfcrik = -0.5f * POC * __sinf(POC * d);

        const float gd = fc * gdR + gfc * dfc + sgf_t * dfcrik;
        const float dot = gux * ux + guy * uy + guz * uz;

        out[base3 + 3 * t + 0] = fmaf(gd, ux, (gux - dot * ux) * invd);
        out[base3 + 3 * t + 1] = fmaf(gd, uy, (guy - dot * uy) * invd);
        out[base3 + 3 * t + 2] = fmaf(gd, uz, (guz - dot * uz) * invd);
    }
}

extern "C" void kernel_launch(void* const* d_in, const int* in_sizes, int n_in,
                              void* d_out, int out_size, void* d_ws, size_t ws_size,
                              hipStream_t stream) {
    (void)in_sizes; (void)n_in; (void)out_size; (void)d_ws; (void)ws_size;
    const float* rij = (const float*)d_in[0];
    // d_in[1] = unique_i (unused: dense K neighbors per atom)
    const float* W1 = (const float*)d_in[2];
    const float* b1 = (const float*)d_in[3];
    const float* W2 = (const float*)d_in[4];
    const float* b2 = (const float*)d_in[5];
    const float* W3 = (const float*)d_in[6];
    const float* b3 = (const float*)d_in[7];
    float* out = (float*)d_out;

    k_prep<<<48, 256, 0, stream>>>(W1, W2);
    k_fused<<<NATOMS, 256, 0, stream>>>(rij, b1, b2, W3, b3, out);
}